// Round 8
// baseline (408.244 us; speedup 1.0000x reference)
//
#include <hip/hip_runtime.h>
#include <hip/hip_bf16.h>

typedef unsigned short u16;
typedef unsigned int u32;
typedef __attribute__((ext_vector_type(8))) short bf16x8;
typedef __attribute__((ext_vector_type(4))) float f32x4;
typedef __attribute__((ext_vector_type(4))) unsigned u32x4;

#define T_STEPS 64
#define BN_TOT  8192
#define BM      32

// workspace byte offsets
#define OFF_WHH0  0u
#define OFF_WIH0  131072u
#define OFF_W1    163840u
#define OFF_B0    425984u
#define OFF_B1    428032u
#define OFF_WEFF  430080u
#define OFF_BEFF  432128u
#define OFF_XB    432192u

// LDS: whh0 frags (128KB) + hA + hB0 + hB1 (8KB each, col-block-major)
#define HB        8192
#define LDS_BYTES (131072 + 3*HB)   // 155648

__device__ __forceinline__ u16 f2bu(float f) {
  unsigned u = __float_as_uint(f);
  unsigned r = (u + 0x7FFFu + ((u >> 16) & 1u)) >> 16;
  return (u16)r;
}
__device__ __forceinline__ float bu2f(u16 u) {
  return __uint_as_float(((unsigned)u) << 16);
}
__device__ __forceinline__ float fsig(float x) {
  return __builtin_amdgcn_rcpf(1.0f + __builtin_amdgcn_exp2f(-1.44269504f * x));
}
__device__ __forceinline__ float ftanh(float x) {
  return 1.0f - 2.0f * __builtin_amdgcn_rcpf(__builtin_amdgcn_exp2f(2.88539008f * x) + 1.0f);
}
__device__ __forceinline__ unsigned cvt_pk_bf16(float lo, float hi) {
  unsigned r;
  asm("v_cvt_pk_bf16_f32 %0, %1, %2" : "=v"(r) : "v"(lo), "v"(hi));
  return r;
}
__device__ __forceinline__ f32x4 mfma16(bf16x8 a, bf16x8 b, f32x4 c) {
  return __builtin_amdgcn_mfma_f32_16x16x32_bf16(a, b, c, 0, 0, 0);
}
// MFMA with B operand pinned in AGPRs -> W1 resident in accumulator file.
__device__ __forceinline__ void mfma_agpr(f32x4& c, const bf16x8& a, const u32x4& b) {
  asm("v_mfma_f32_16x16x32_bf16 %0, %1, %2, %0" : "+v"(c) : "v"(a), "a"(b));
}

union U16x8 { u16 u[8]; uint4 q; };

// ---------------- prep: weights -> fragment-ordered bf16, collapsed head ----
__global__ void lstm_prep_w(const float* Wih0, const float* Whh0,
                            const float* bih0, const float* bhh0,
                            const float* Wih1, const float* Whh1,
                            const float* bih1, const float* bhh1,
                            const float* muW1, const float* mub1,
                            const float* muW2, const float* mub2,
                            const float* sgW1, const float* sgb1,
                            const float* sgW2, const float* sgb2,
                            unsigned char* ws)
{
  int id = blockIdx.x * 256 + threadIdx.x;
  u16* whh0_f = (u16*)(ws + OFF_WHH0);
  u16* wih0_f = (u16*)(ws + OFF_WIH0);
  u16* w1_f   = (u16*)(ws + OFF_W1);
  float* b0   = (float*)(ws + OFF_B0);
  float* b1   = (float*)(ws + OFF_B1);
  float* weff = (float*)(ws + OFF_WEFF);
  float* beff = (float*)(ws + OFF_BEFF);

  if (id < 8192) {                       // Whh0 frags: [w][g][kf][lane][8]
    int fid = id >> 6, lane = id & 63;
    int w = fid >> 4, g = (fid >> 2) & 3, kf = fid & 3;
    int r = g*128 + w*16 + (lane & 15);
    int k = kf*32 + (lane >> 4)*8;
    const float* src = Whh0 + r*128 + k;
    U16x8 t;
    #pragma unroll
    for (int i = 0; i < 8; ++i) t.u[i] = f2bu(src[i]);
    ((uint4*)whh0_f)[id] = t.q;
  } else if (id < 10240) {               // Wih0 frags (K=8 in 32, zero-padded)
    int c = id - 8192; int fid = c >> 6, lane = c & 63;
    int w = fid >> 2, g = fid & 3;
    U16x8 t;
    #pragma unroll
    for (int i = 0; i < 8; ++i) t.u[i] = 0;
    if (lane < 16) {
      int r = g*128 + w*16 + lane;
      #pragma unroll
      for (int i = 0; i < 8; ++i) t.u[i] = f2bu(Wih0[r*8 + i]);
    }
    ((uint4*)wih0_f)[c] = t.q;
  } else if (id < 26624) {               // W1 = [Wih1 ; Whh1] frags, K=256
    int c = id - 10240; int fid = c >> 6, lane = c & 63;
    int w = fid >> 5, g = (fid >> 3) & 3, kf = fid & 7;
    int r = g*128 + w*16 + (lane & 15);
    int k = kf*32 + (lane >> 4)*8;
    const float* src = (k < 128) ? (Wih1 + r*128 + k) : (Whh1 + r*128 + (k-128));
    U16x8 t;
    #pragma unroll
    for (int i = 0; i < 8; ++i) t.u[i] = f2bu(src[i]);
    ((uint4*)w1_f)[c] = t.q;
  } else if (id < 27136) {               // b0 arranged
    int i = id - 26624; int w = i >> 6, g = (i >> 4) & 3, cc = i & 15;
    int r = g*128 + w*16 + cc;
    b0[i] = bih0[r] + bhh0[r];
  } else if (id < 27648) {               // b1 arranged
    int i = id - 27136; int w = i >> 6, g = (i >> 4) & 3, cc = i & 15;
    int r = g*128 + w*16 + cc;
    b1[i] = bih1[r] + bhh1[r];
  } else if (id < 28160) {               // collapsed head W: [4][128]
    int i = id - 27648; int o = i >> 7, k = i & 127;
    const float* W1p = (o < 2) ? muW1 : sgW1;
    const float* W2p = (o < 2) ? muW2 : sgW2;
    int oo = o & 1;
    float s = 0.f;
    for (int m = 0; m < 64; ++m) s += W2p[oo*64 + m] * W1p[m*128 + k];
    weff[i] = s;
  } else if (id < 28164) {               // collapsed head bias [4]
    int o = id - 28160; int oo = o & 1;
    const float* W2p = (o < 2) ? muW2 : sgW2;
    const float* b1p = (o < 2) ? mub1 : sgb1;
    const float* b2p = (o < 2) ? mub2 : sgb2;
    float s = b2p[oo];
    for (int m = 0; m < 64; ++m) s += W2p[oo*64 + m] * b1p[m];
    beff[o] = s;
  }
}

// ---------------- prep: in_tensor [B,T,N,D] fp32 -> xb [T, BN, 8] bf16 ------
__global__ void lstm_prep_x(const float* in, unsigned char* ws)
{
  int id = blockIdx.x * 256 + threadIdx.x;     // < 524288
  if (id >= T_STEPS * BN_TOT) return;
  int t = id >> 13, s = id & 8191, b = s >> 9, n = s & 511;
  const float* src = in + (((b*64) + t)*512 + n)*8;
  U16x8 v;
  #pragma unroll
  for (int i = 0; i < 8; ++i) v.u[i] = f2bu(src[i]);
  *(uint4*)(ws + OFF_XB + (size_t)id * 16) = v.q;
}

// ---------------- main: fused 2-layer LSTM, rotated overlap schedule --------
// body(t) = [L0m(t) || ACT1(t-1)]  bar1  [ACT0(t)]  bar2  [L1m(t)]
// - L0m(t) reads hA(t-1), x(t); ACT1(t-1) writes hB(t-1): independent -> the
//   scheduler hides ACT1's trans ops under L0m's 40 MFMAs.
// - hA single-buffered: writer ACT0 (between bars); readers L1m(t) after bar2
//   and L0m(t+1) before next bar1 -> every RAW/WAR crosses >=1 barrier.
// - hB double-buffered by t parity: ACT1(t-1) writes buf(t&1) in seg1, L1m(t)
//   reads it in seg3 (2 bars later); WAR vs L1m(t-2) crosses body(t-1) bars.
// h layout: col-block-major, addr(row,col) = (col>>3)*512 + row*16 + (col&7)*2
#define ACT_MF(A, CS, HBASE, MF)                                     \
  { float hq[4];                                                     \
    _Pragma("unroll")                                                \
    for (int q = 0; q < 4; ++q) {                                    \
      float gi = fsig(A[0][q]);                                      \
      float gf = fsig(A[1][q]);                                      \
      float gg = ftanh(A[2][q]);                                     \
      float go = fsig(A[3][q]);                                      \
      float c  = gf * CS[q] + gi * gg;                               \
      CS[q] = c;                                                     \
      hq[q] = go * ftanh(c);                                         \
    }                                                                \
    unsigned p01 = cvt_pk_bf16(hq[0], hq[1]);                        \
    unsigned p23 = cvt_pk_bf16(hq[2], hq[3]);                        \
    int rb = ((MF)*16 + lk*4);                                       \
    *(u16*)((HBASE) + wb + (rb  )*16) = (u16)p01;                    \
    *(u16*)((HBASE) + wb + (rb+1)*16) = (u16)(p01 >> 16);            \
    *(u16*)((HBASE) + wb + (rb+2)*16) = (u16)p23;                    \
    *(u16*)((HBASE) + wb + (rb+3)*16) = (u16)(p23 >> 16);            \
  }

// one kf-group of layer-0 hh MFMAs (builtin, B from whh0 LDS frags)
#define L0M_KF(KF)                                                   \
  { bf16x8 a0 = *(const bf16x8*)(hA + ((KF)*4)*512 + ra);            \
    bf16x8 a1 = *(const bf16x8*)(hA + ((KF)*4)*512 + ra + 256);      \
    _Pragma("unroll")                                                \
    for (int g = 0; g < 4; ++g) {                                    \
      bf16x8 bfr = *(const bf16x8*)(whh0_lds + ((w*16 + g*4 + (KF))*64 + l)*8); \
      acc0[0][g] = mfma16(a0, bfr, acc0[0][g]);                      \
      acc0[1][g] = mfma16(a1, bfr, acc0[1][g]);                      \
    } }

// one kf-group of layer-1 MFMAs (asm, B=W1 frag in AGPR)
#define L1M_KF(HS, KF2, WKF)                                         \
  { bf16x8 a0 = *(const bf16x8*)((HS) + ((KF2)*4)*512 + ra);         \
    bf16x8 a1 = *(const bf16x8*)((HS) + ((KF2)*4)*512 + ra + 256);   \
    _Pragma("unroll")                                                \
    for (int g = 0; g < 4; ++g) {                                    \
      mfma_agpr(acc1[0][g], a0, w1a[g][WKF]);                        \
      mfma_agpr(acc1[1][g], a1, w1a[g][WKF]);                        \
    } }

__global__ __launch_bounds__(512, 2) void lstm_fused(const unsigned char* ws, float* out)
{
  extern __shared__ unsigned char lds[];
  u16* whh0_lds = (u16*)lds;                 // [w][g][kf][lane][8] frags, 128KB
  unsigned char* hA  = lds + 131072;
  unsigned char* hB0 = hA + HB;
  unsigned char* hB1 = hB0 + HB;

  const u16* whh0_f = (const u16*)(ws + OFF_WHH0);
  const u16* wih0_f = (const u16*)(ws + OFF_WIH0);
  const u16* w1_f   = (const u16*)(ws + OFF_W1);
  const float* b0a  = (const float*)(ws + OFF_B0);
  const float* b1a  = (const float*)(ws + OFF_B1);
  const float* weff = (const float*)(ws + OFF_WEFF);
  const float* beff = (const float*)(ws + OFF_BEFF);
  const u16* xb     = (const u16*)(ws + OFF_XB);

  const int tid = threadIdx.x;
  const int w = tid >> 6, l = tid & 63;
  const int lrow = l & 15, lk = l >> 4;
  const int s0 = blockIdx.x * BM;
  const int wb = (w*2 + (lrow >> 3))*512 + (lrow & 7)*2;   // ACT write base
  const int ra = lk*512 + lrow*16;                          // A-read base

  // ---- prologue ------------------------------------------------------------
  #pragma unroll 2
  for (int i = tid; i < 8192; i += 512)
    ((uint4*)whh0_lds)[i] = ((const uint4*)whh0_f)[i];
  for (int i = tid; i < 6144; i += 512) ((u32*)hA)[i] = 0;   // hA,hB0,hB1
  __builtin_amdgcn_sched_barrier(0);

  u32x4 w1a[4][8];                       // -> AGPR (128), batched loads
  #pragma unroll
  for (int kf = 0; kf < 8; ++kf) {
    #pragma unroll
    for (int g = 0; g < 4; ++g)
      w1a[g][kf] = *(const u32x4*)(w1_f + ((((w*4+g)*8)+kf)*64 + l)*8);
    __builtin_amdgcn_sched_barrier(0);
  }
  bf16x8 wih0r[4];
  #pragma unroll
  for (int g = 0; g < 4; ++g)
    wih0r[g] = *(const bf16x8*)(wih0_f + ((w*4+g)*64 + l)*8);
  float b0v[4], b1v[4];
  #pragma unroll
  for (int g = 0; g < 4; ++g) {
    b0v[g] = b0a[w*64 + g*16 + lrow];
    b1v[g] = b1a[w*64 + g*16 + lrow];
  }
  float c_a[2][4] = {{0,0,0,0},{0,0,0,0}};
  float c_b[2][4] = {{0,0,0,0},{0,0,0,0}};
  f32x4 acc0[2][4], acc1[2][4];

  __syncthreads();

  // ---- peel t=0: hA==0 so skip the hh MFMAs; no ACT1 yet -------------------
  {
    const u16* xrow = xb + (size_t)(s0 + lrow)*8;
    bf16x8 xf0 = *(const bf16x8*)xrow;          // lk>0 lanes: B rows >=8 are 0
    bf16x8 xf1 = *(const bf16x8*)(xrow + 128);
    #pragma unroll
    for (int g = 0; g < 4; ++g) {
      acc0[0][g] = (f32x4){b0v[g], b0v[g], b0v[g], b0v[g]};
      acc0[1][g] = (f32x4){b0v[g], b0v[g], b0v[g], b0v[g]};
    }
    #pragma unroll
    for (int g = 0; g < 4; ++g) {
      acc0[0][g] = mfma16(xf0, wih0r[g], acc0[0][g]);
      acc0[1][g] = mfma16(xf1, wih0r[g], acc0[1][g]);
    }
    ACT_MF(acc0[0], c_a[0], hA, 0);
    ACT_MF(acc0[1], c_a[1], hA, 1);
    __syncthreads();                        // hA(0) visible
    #pragma unroll
    for (int g = 0; g < 4; ++g) {
      acc1[0][g] = (f32x4){b1v[g], b1v[g], b1v[g], b1v[g]};
      acc1[1][g] = (f32x4){b1v[g], b1v[g], b1v[g], b1v[g]};
    }
    asm volatile("s_nop 1");
    #pragma unroll
    for (int kf = 0; kf < 4; ++kf) L1M_KF(hA, kf, kf);
    #pragma unroll
    for (int kf = 0; kf < 4; ++kf) L1M_KF(hB0, kf, kf + 4);   // hB(-1)=0
    asm volatile("s_nop 7\ns_nop 7");
  }

  // ---- main loop (t = 1..63), branchless body ------------------------------
  #pragma unroll 1
  for (int t = 1; t < T_STEPS; ++t) {
    unsigned char* hb = (t & 1) ? hB1 : hB0;   // ACT1(t-1) dst == L1m(t) src

    // seg1: L0m(t) MFMAs || ACT1(t-1)  (independent -> scheduler overlaps)
    const u16* xrow = xb + (size_t)(t*8192 + s0 + lrow)*8;
    bf16x8 xf0 = *(const bf16x8*)xrow;
    bf16x8 xf1 = *(const bf16x8*)(xrow + 128);
    #pragma unroll
    for (int g = 0; g < 4; ++g) {
      acc0[0][g] = (f32x4){b0v[g], b0v[g], b0v[g], b0v[g]};
      acc0[1][g] = (f32x4){b0v[g], b0v[g], b0v[g], b0v[g]};
    }
    L0M_KF(0)
    L0M_KF(1)
    ACT_MF(acc1[0], c_b[0], hb, 0);            // frees acc1[0]
    L0M_KF(2)
    L0M_KF(3)
    ACT_MF(acc1[1], c_b[1], hb, 1);            // frees acc1[1]
    #pragma unroll
    for (int g = 0; g < 4; ++g) {
      acc0[0][g] = mfma16(xf0, wih0r[g], acc0[0][g]);
      acc0[1][g] = mfma16(xf1, wih0r[g], acc0[1][g]);
    }
    __syncthreads();                           // bar1: hA readers + hB write done

    // seg2: ACT0(t) -> hA(t)
    ACT_MF(acc0[0], c_a[0], hA, 0);
    ACT_MF(acc0[1], c_a[1], hA, 1);
    __syncthreads();                           // bar2: hA(t) visible

    // seg3: L1m(t) = b1 + hA(t)@Wih1 + hB(t-1)@Whh1   (W1 in AGPRs)
    #pragma unroll
    for (int g = 0; g < 4; ++g) {
      acc1[0][g] = (f32x4){b1v[g], b1v[g], b1v[g], b1v[g]};
      acc1[1][g] = (f32x4){b1v[g], b1v[g], b1v[g], b1v[g]};
    }
    asm volatile("s_nop 1");
    #pragma unroll
    for (int kf = 0; kf < 4; ++kf) L1M_KF(hA, kf, kf);
    #pragma unroll
    for (int kf = 0; kf < 4; ++kf) L1M_KF(hb, kf, kf + 4);
    asm volatile("s_nop 7\ns_nop 7");          // asm MFMA -> VALU acc1 reads
  }

  // ---- epilogue: ACT1(63) -> hB0 (t=64 parity), then head ------------------
  ACT_MF(acc1[0], c_b[0], hB0, 0);
  ACT_MF(acc1[1], c_b[1], hB0, 1);
  __syncthreads();

  if (tid < BM*4) {
    int m = tid >> 2, o = tid & 3;
    const float* wr = weff + o*128;
    float d = beff[o];
    #pragma unroll 4
    for (int kk = 0; kk < 16; ++kk) {
      bf16x8 hv = *(const bf16x8*)(hB0 + kk*512 + m*16);
      #pragma unroll
      for (int j = 0; j < 8; ++j) d += bu2f((u16)hv[j]) * wr[kk*8 + j];
    }
    float v = fsig(d);
    if (o >= 2) v *= 0.5f;
    int s = s0 + m;
    out[(o >= 2 ? 16384 : 0) + s*2 + (o & 1)] = v;
  }
}

extern "C" void kernel_launch(void* const* d_in, const int* in_sizes, int n_in,
                              void* d_out, int out_size, void* d_ws, size_t ws_size,
                              hipStream_t stream) {
  (void)in_sizes; (void)n_in; (void)out_size; (void)ws_size;
  const float* in_tensor = (const float*)d_in[0];
  const float* Wih0 = (const float*)d_in[1];
  const float* Whh0 = (const float*)d_in[2];
  const float* bih0 = (const float*)d_in[3];
  const float* bhh0 = (const float*)d_in[4];
  const float* Wih1 = (const float*)d_in[5];
  const float* Whh1 = (const float*)d_in[6];
  const float* bih1 = (const float*)d_in[7];
  const float* bhh1 = (const float*)d_in[8];
  const float* muW1 = (const float*)d_in[9];
  const float* mub1 = (const float*)d_in[10];
  const float* muW2 = (const float*)d_in[11];
  const float* mub2 = (const float*)d_in[12];
  const float* sgW1 = (const float*)d_in[13];
  const float* sgb1 = (const float*)d_in[14];
  const float* sgW2 = (const float*)d_in[15];
  const float* sgb2 = (const float*)d_in[16];
  unsigned char* ws = (unsigned char*)d_ws;
  float* out = (float*)d_out;

  lstm_prep_w<<<dim3(111), dim3(256), 0, stream>>>(
      Wih0, Whh0, bih0, bhh0, Wih1, Whh1, bih1, bhh1,
      muW1, mub1, muW2, mub2, sgW1, sgb1, sgW2, sgb2, ws);
  lstm_prep_x<<<dim3(2048), dim3(256), 0, stream>>>(in_tensor, ws);

  (void)hipFuncSetAttribute((const void*)lstm_fused,
                            hipFuncAttributeMaxDynamicSharedMemorySize, LDS_BYTES);
  lstm_fused<<<dim3(256), dim3(512), LDS_BYTES, stream>>>(ws, out);
}

// Round 9
// 270.812 us; speedup vs baseline: 1.5075x; 1.5075x over previous
//
#include <hip/hip_runtime.h>
#include <hip/hip_bf16.h>

typedef unsigned short u16;
typedef unsigned int u32;
typedef __attribute__((ext_vector_type(8))) short bf16x8;
typedef __attribute__((ext_vector_type(4))) float f32x4;

#define T_STEPS 64
#define BN_TOT  8192
#define BM      32

// workspace byte offsets
#define OFF_WHH0  0u
#define OFF_WIH0  131072u
#define OFF_W1    163840u
#define OFF_B0    425984u
#define OFF_B1    428032u
#define OFF_WEFF  430080u
#define OFF_BEFF  432128u
#define OFF_XB    432192u

// LDS: whh0 frags (128KB) + hA + hB0 + hB1 (8KB each, col-block-major)
#define HB        8192
#define LDS_BYTES (131072 + 3*HB)   // 155648

__device__ __forceinline__ u16 f2bu(float f) {
  unsigned u = __float_as_uint(f);
  unsigned r = (u + 0x7FFFu + ((u >> 16) & 1u)) >> 16;
  return (u16)r;
}
__device__ __forceinline__ float bu2f(u16 u) {
  return __uint_as_float(((unsigned)u) << 16);
}
// fast sigmoid/tanh: v_exp_f32 (2^x) + v_rcp_f32, saturate correctly at +-inf
__device__ __forceinline__ float fsig(float x) {
  return __builtin_amdgcn_rcpf(1.0f + __builtin_amdgcn_exp2f(-1.44269504f * x));
}
__device__ __forceinline__ float ftanh(float x) {
  return 1.0f - 2.0f * __builtin_amdgcn_rcpf(__builtin_amdgcn_exp2f(2.88539008f * x) + 1.0f);
}
__device__ __forceinline__ unsigned cvt_pk_bf16(float lo, float hi) {
  unsigned r;
  asm("v_cvt_pk_bf16_f32 %0, %1, %2" : "=v"(r) : "v"(lo), "v"(hi));
  return r;
}
__device__ __forceinline__ f32x4 mfma16(bf16x8 a, bf16x8 b, f32x4 c) {
  return __builtin_amdgcn_mfma_f32_16x16x32_bf16(a, b, c, 0, 0, 0);
}

union U16x8 { u16 u[8]; uint4 q; };

// ---------------- prep: weights -> fragment-ordered bf16, collapsed head ----
__global__ void lstm_prep_w(const float* Wih0, const float* Whh0,
                            const float* bih0, const float* bhh0,
                            const float* Wih1, const float* Whh1,
                            const float* bih1, const float* bhh1,
                            const float* muW1, const float* mub1,
                            const float* muW2, const float* mub2,
                            const float* sgW1, const float* sgb1,
                            const float* sgW2, const float* sgb2,
                            unsigned char* ws)
{
  int id = blockIdx.x * 256 + threadIdx.x;
  u16* whh0_f = (u16*)(ws + OFF_WHH0);
  u16* wih0_f = (u16*)(ws + OFF_WIH0);
  u16* w1_f   = (u16*)(ws + OFF_W1);
  float* b0   = (float*)(ws + OFF_B0);
  float* b1   = (float*)(ws + OFF_B1);
  float* weff = (float*)(ws + OFF_WEFF);
  float* beff = (float*)(ws + OFF_BEFF);

  if (id < 8192) {                       // Whh0 frags: [w][g][kf][lane][8]
    int fid = id >> 6, lane = id & 63;
    int w = fid >> 4, g = (fid >> 2) & 3, kf = fid & 3;
    int r = g*128 + w*16 + (lane & 15);
    int k = kf*32 + (lane >> 4)*8;
    const float* src = Whh0 + r*128 + k;
    U16x8 t;
    #pragma unroll
    for (int i = 0; i < 8; ++i) t.u[i] = f2bu(src[i]);
    ((uint4*)whh0_f)[id] = t.q;
  } else if (id < 10240) {               // Wih0 frags (K=8 in 32, zero-padded)
    int c = id - 8192; int fid = c >> 6, lane = c & 63;
    int w = fid >> 2, g = fid & 3;
    U16x8 t;
    #pragma unroll
    for (int i = 0; i < 8; ++i) t.u[i] = 0;
    if (lane < 16) {
      int r = g*128 + w*16 + lane;
      #pragma unroll
      for (int i = 0; i < 8; ++i) t.u[i] = f2bu(Wih0[r*8 + i]);
    }
    ((uint4*)wih0_f)[c] = t.q;
  } else if (id < 26624) {               // W1 = [Wih1 ; Whh1] frags, K=256
    int c = id - 10240; int fid = c >> 6, lane = c & 63;
    int w = fid >> 5, g = (fid >> 3) & 3, kf = fid & 7;
    int r = g*128 + w*16 + (lane & 15);
    int k = kf*32 + (lane >> 4)*8;
    const float* src = (k < 128) ? (Wih1 + r*128 + k) : (Whh1 + r*128 + (k-128));
    U16x8 t;
    #pragma unroll
    for (int i = 0; i < 8; ++i) t.u[i] = f2bu(src[i]);
    ((uint4*)w1_f)[c] = t.q;
  } else if (id < 27136) {               // b0 arranged
    int i = id - 26624; int w = i >> 6, g = (i >> 4) & 3, cc = i & 15;
    int r = g*128 + w*16 + cc;
    b0[i] = bih0[r] + bhh0[r];
  } else if (id < 27648) {               // b1 arranged
    int i = id - 27136; int w = i >> 6, g = (i >> 4) & 3, cc = i & 15;
    int r = g*128 + w*16 + cc;
    b1[i] = bih1[r] + bhh1[r];
  } else if (id < 28160) {               // collapsed head W: [4][128]
    int i = id - 27648; int o = i >> 7, k = i & 127;
    const float* W1p = (o < 2) ? muW1 : sgW1;
    const float* W2p = (o < 2) ? muW2 : sgW2;
    int oo = o & 1;
    float s = 0.f;
    for (int m = 0; m < 64; ++m) s += W2p[oo*64 + m] * W1p[m*128 + k];
    weff[i] = s;
  } else if (id < 28164) {               // collapsed head bias [4]
    int o = id - 28160; int oo = o & 1;
    const float* W2p = (o < 2) ? muW2 : sgW2;
    const float* b1p = (o < 2) ? mub1 : sgb1;
    const float* b2p = (o < 2) ? mub2 : sgb2;
    float s = b2p[oo];
    for (int m = 0; m < 64; ++m) s += W2p[oo*64 + m] * b1p[m];
    beff[o] = s;
  }
}

// ---------------- prep: in_tensor [B,T,N,D] fp32 -> xb [T, BN, 8] bf16 ------
__global__ void lstm_prep_x(const float* in, unsigned char* ws)
{
  int id = blockIdx.x * 256 + threadIdx.x;     // < 524288
  if (id >= T_STEPS * BN_TOT) return;
  int t = id >> 13, s = id & 8191, b = s >> 9, n = s & 511;
  const float* src = in + (((b*64) + t)*512 + n)*8;
  U16x8 v;
  #pragma unroll
  for (int i = 0; i < 8; ++i) v.u[i] = f2bu(src[i]);
  *(uint4*)(ws + OFF_XB + (size_t)id * 16) = v.q;
}

// ---------------- main: fused 2-layer LSTM + head (R2 structure) ------------
// R9 = R2 (best known: 280us) with ONE change: col-block-major h layout.
//   addr(row, col) = (col>>3)*512 + row*16 + (col&7)*2
// A-frag b128 read (16 lanes, rows 0..15 contiguous 16B): conflict-free.
// ACT u16 store: ~2-4 way. Measured in R5/R6: 4.19e6 vs 1.26e7 (R2 HPAD).
// Everything else is byte-for-byte R2: builtin MFMAs (compiler manages w1r
// placement -> AGPR, zero spill), xf cross-step prefetch, 3 barriers/step.
#define ACT_BLOCK(ACC, CS, HBASE)                                   \
  { _Pragma("unroll")                                               \
    for (int mf = 0; mf < 2; ++mf) {                                \
      float hq[4];                                                  \
      _Pragma("unroll")                                             \
      for (int q = 0; q < 4; ++q) {                                 \
        float gi = fsig(ACC[mf][0][q]);                             \
        float gf = fsig(ACC[mf][1][q]);                             \
        float gg = ftanh(ACC[mf][2][q]);                            \
        float go = fsig(ACC[mf][3][q]);                             \
        float c  = gf * CS[mf][q] + gi * gg;                        \
        CS[mf][q] = c;                                              \
        hq[q] = go * ftanh(c);                                      \
      }                                                             \
      unsigned p01 = cvt_pk_bf16(hq[0], hq[1]);                     \
      unsigned p23 = cvt_pk_bf16(hq[2], hq[3]);                     \
      int rb = (mf*16 + lk*4);                                      \
      *(u16*)((HBASE) + wb + (rb  )*16) = (u16)p01;                 \
      *(u16*)((HBASE) + wb + (rb+1)*16) = (u16)(p01 >> 16);         \
      *(u16*)((HBASE) + wb + (rb+2)*16) = (u16)p23;                 \
      *(u16*)((HBASE) + wb + (rb+3)*16) = (u16)(p23 >> 16);         \
    } }

__global__ __launch_bounds__(512, 2) void lstm_fused(const unsigned char* ws, float* out)
{
  extern __shared__ unsigned char lds[];
  u16* whh0_lds = (u16*)lds;                 // [w][g][kf][lane][8] frags, 128KB
  unsigned char* hA  = lds + 131072;
  unsigned char* hB0 = hA + HB;
  unsigned char* hB1 = hB0 + HB;

  const u16* whh0_f = (const u16*)(ws + OFF_WHH0);
  const u16* wih0_f = (const u16*)(ws + OFF_WIH0);
  const u16* w1_f   = (const u16*)(ws + OFF_W1);
  const float* b0a  = (const float*)(ws + OFF_B0);
  const float* b1a  = (const float*)(ws + OFF_B1);
  const float* weff = (const float*)(ws + OFF_WEFF);
  const float* beff = (const float*)(ws + OFF_BEFF);
  const u16* xb     = (const u16*)(ws + OFF_XB);

  const int tid = threadIdx.x;
  const int w = tid >> 6, l = tid & 63;
  const int lrow = l & 15, lk = l >> 4;
  const int s0 = blockIdx.x * BM;
  // per-thread byte bases into col-block-major h buffers
  const int wb = (w*2 + (lrow >> 3))*512 + (lrow & 7)*2;   // ACT write base
  const int ra = lk*512 + lrow*16;                          // A-read base

  // stage Whh0 frags into LDS (straight 16B copies, layout identical)
  for (int i = tid; i < 8192; i += 512)
    ((uint4*)whh0_lds)[i] = ((const uint4*)whh0_f)[i];
  // zero all three h buffers (contiguous 24KB)
  for (int i = tid; i < 6144; i += 512) ((u32*)hA)[i] = 0;

  // persistent register weights: layer-1 (K=256) + Wih0 pad-frags + biases.
  // Plain arrays, builtin consumers: the compiler places w1r in AGPRs itself
  // (R2 evidence: VGPR=128, WRITE_SIZE=128KB -> no spill, no refetch).
  bf16x8 w1r[4][8];
  #pragma unroll
  for (int g = 0; g < 4; ++g)
    #pragma unroll
    for (int kf = 0; kf < 8; ++kf)
      w1r[g][kf] = *(const bf16x8*)(w1_f + ((((w*4+g)*8)+kf)*64 + l)*8);
  bf16x8 wih0r[4];
  #pragma unroll
  for (int g = 0; g < 4; ++g)
    wih0r[g] = *(const bf16x8*)(wih0_f + ((w*4+g)*64 + l)*8);
  float b0v[4], b1v[4];
  #pragma unroll
  for (int g = 0; g < 4; ++g) {
    b0v[g] = b0a[w*64 + g*16 + lrow];
    b1v[g] = b1a[w*64 + g*16 + lrow];
  }
  float c_a[2][4] = {{0,0,0,0},{0,0,0,0}};
  float c_b[2][4] = {{0,0,0,0},{0,0,0,0}};

  unsigned char* hbR = hB0;   // layer-1 h_prev (zero at t=0)
  unsigned char* hbW = hB1;

  // x software pipeline: xf holds step t's fragment; loaded one phase early
  bf16x8 xf0 = {0,0,0,0,0,0,0,0}, xf1 = {0,0,0,0,0,0,0,0};
  if (lk == 0) {
    xf0 = *(const bf16x8*)(xb + (size_t)(s0 + lrow)*8);
    xf1 = *(const bf16x8*)(xb + (size_t)(s0 + 16 + lrow)*8);
  }
  __syncthreads();

  #pragma unroll 1
  for (int t = 0; t < T_STEPS; ++t) {
    // ---- layer 0: gates = b0 + x@Wih0^T + hA@Whh0^T -----------------------
    f32x4 acc[2][4];
    #pragma unroll
    for (int g = 0; g < 4; ++g) {
      acc[0][g] = (f32x4){b0v[g], b0v[g], b0v[g], b0v[g]};
      acc[1][g] = (f32x4){b0v[g], b0v[g], b0v[g], b0v[g]};
    }
    #pragma unroll
    for (int g = 0; g < 4; ++g) {
      acc[0][g] = mfma16(xf0, wih0r[g], acc[0][g]);
      acc[1][g] = mfma16(xf1, wih0r[g], acc[1][g]);
    }
    // prefetch next step's x (L2 latency hides under the rest of the step)
    if (t + 1 < T_STEPS && lk == 0) {
      xf0 = *(const bf16x8*)(xb + (size_t)((t+1)*8192 + s0 + lrow)*8);
      xf1 = *(const bf16x8*)(xb + (size_t)((t+1)*8192 + s0 + 16 + lrow)*8);
    }
    #pragma unroll
    for (int kf = 0; kf < 4; ++kf) {
      bf16x8 a0 = *(const bf16x8*)(hA + (kf*4 + lk)*512 + lrow*16);
      bf16x8 a1 = *(const bf16x8*)(hA + (kf*4 + lk)*512 + (16 + lrow)*16);
      #pragma unroll
      for (int g = 0; g < 4; ++g) {
        bf16x8 bfr = *(const bf16x8*)(whh0_lds + ((w*16 + g*4 + kf)*64 + l)*8);
        acc[0][g] = mfma16(a0, bfr, acc[0][g]);
        acc[1][g] = mfma16(a1, bfr, acc[1][g]);
      }
    }
    __syncthreads();                       // (1) WAR: hA reads done
    ACT_BLOCK(acc, c_a, hA);               // act0 -> hA (new layer-0 h)
    __syncthreads();                       // (2) RAW: new hA visible

    // ---- layer 1: gates = b1 + hA@Wih1^T + hbR@Whh1^T (K=256 in regs) ----
    #pragma unroll
    for (int g = 0; g < 4; ++g) {
      acc[0][g] = (f32x4){b1v[g], b1v[g], b1v[g], b1v[g]};
      acc[1][g] = (f32x4){b1v[g], b1v[g], b1v[g], b1v[g]};
    }
    #pragma unroll
    for (int kf = 0; kf < 8; ++kf) {
      const unsigned char* hs = (kf < 4) ? hA : hbR;
      bf16x8 a0 = *(const bf16x8*)(hs + ((kf & 3)*4 + lk)*512 + lrow*16);
      bf16x8 a1 = *(const bf16x8*)(hs + ((kf & 3)*4 + lk)*512 + (16 + lrow)*16);
      #pragma unroll
      for (int g = 0; g < 4; ++g) {
        acc[0][g] = mfma16(a0, w1r[g][kf], acc[0][g]);
        acc[1][g] = mfma16(a1, w1r[g][kf], acc[1][g]);
      }
    }
    // writes go to hbW (ping-pong buffer) -> no WAR barrier needed here
    ACT_BLOCK(acc, c_b, hbW);              // act1 -> hB[t&1]
    __syncthreads();                       // (3) RAW: new hB visible
    { unsigned char* tp = hbR; hbR = hbW; hbW = tp; }
  }

  // ---- head: out = sigmoid(h_final @ Weff^T + beff), sigma *= 0.5 ----------
  if (tid < BM*4) {
    int m = tid >> 2, o = tid & 3;
    const float* wr = weff + o*128;
    float d = beff[o];
    #pragma unroll 4
    for (int kk = 0; kk < 16; ++kk) {
      bf16x8 hv = *(const bf16x8*)(hbR + kk*512 + m*16);
      #pragma unroll
      for (int j = 0; j < 8; ++j) d += bu2f((u16)hv[j]) * wr[kk*8 + j];
    }
    float v = fsig(d);
    if (o >= 2) v *= 0.5f;
    int s = s0 + m;
    out[(o >= 2 ? 16384 : 0) + s*2 + (o & 1)] = v;
  }
}

extern "C" void kernel_launch(void* const* d_in, const int* in_sizes, int n_in,
                              void* d_out, int out_size, void* d_ws, size_t ws_size,
                              hipStream_t stream) {
  (void)in_sizes; (void)n_in; (void)out_size; (void)ws_size;
  const float* in_tensor = (const float*)d_in[0];
  const float* Wih0 = (const float*)d_in[1];
  const float* Whh0 = (const float*)d_in[2];
  const float* bih0 = (const float*)d_in[3];
  const float* bhh0 = (const float*)d_in[4];
  const float* Wih1 = (const float*)d_in[5];
  const float* Whh1 = (const float*)d_in[6];
  const float* bih1 = (const float*)d_in[7];
  const float* bhh1 = (const float*)d_in[8];
  const float* muW1 = (const float*)d_in[9];
  const float* mub1 = (const float*)d_in[10];
  const float* muW2 = (const float*)d_in[11];
  const float* mub2 = (const float*)d_in[12];
  const float* sgW1 = (const float*)d_in[13];
  const float* sgb1 = (const float*)d_in[14];
  const float* sgW2 = (const float*)d_in[15];
  const float* sgb2 = (const float*)d_in[16];
  unsigned char* ws = (unsigned char*)d_ws;
  float* out = (float*)d_out;

  lstm_prep_w<<<dim3(111), dim3(256), 0, stream>>>(
      Wih0, Whh0, bih0, bhh0, Wih1, Whh1, bih1, bhh1,
      muW1, mub1, muW2, mub2, sgW1, sgb1, sgW2, sgb2, ws);
  lstm_prep_x<<<dim3(2048), dim3(256), 0, stream>>>(in_tensor, ws);

  (void)hipFuncSetAttribute((const void*)lstm_fused,
                            hipFuncAttributeMaxDynamicSharedMemorySize, LDS_BYTES);
  lstm_fused<<<dim3(256), dim3(512), LDS_BYTES, stream>>>(ws, out);
}